// Round 4
// baseline (85.468 us; speedup 1.0000x reference)
//
#include <hip/hip_runtime.h>

#define BATCH  8
#define NPTS   4096
#define NSLICE 32                 // target-set split per (dir,b)
#define SLICE  (NPTS / NSLICE)    // 128 targets per block
#define TPB1   512                // 8 waves/block, 2 blocks/CU
#define QPT    8                  // queries per thread (4096 / 512)
#define BIAS   1000.0f            // makes e positive -> uint-ordered atomicMin

// Stage 1: grid = 2 dirs x 8 batches x 32 target-slices = 512 blocks.
// ALL per-thread state is in NAMED scalars (no arrays at all) — the AMD
// backend was placing float[8] locals in scratch (256 B/thread, 64 MB of
// HBM writes). Inner loop: 1 broadcast ds_read_b128 feeds 8x(3 fma + 1 min).
__global__ __launch_bounds__(TPB1, 4) void chamfer_stage1(
    const float* __restrict__ preds,
    const float* __restrict__ gts,
    unsigned int* __restrict__ umin)
{
    const int blk   = blockIdx.x;
    const int slice = blk % NSLICE;
    const int db    = blk / NSLICE;    // dir*8 + b
    const int dir   = db >> 3;
    const int b     = db & 7;

    const float* Q = dir ? gts   : preds;   // query set
    const float* T = dir ? preds : gts;     // target set

    __shared__ float4 sT[SLICE];            // 2 KiB

    const float* Tb = T + ((size_t)b * NPTS + slice * SLICE) * 3;
    if (threadIdx.x < SLICE) {
        const int j = threadIdx.x;
        const float y0 = Tb[j * 3 + 0];
        const float y1 = Tb[j * 3 + 1];
        const float y2 = Tb[j * 3 + 2];
        sT[j] = make_float4(-2.0f * y0, -2.0f * y1, -2.0f * y2,
                            y0 * y0 + y1 * y1 + y2 * y2);
    }

    // This thread's 8 consecutive queries (24 floats = 6 float4), unpacked
    // into 24 named scalars.
    const int q0 = threadIdx.x * QPT;
    const float4* p4 = reinterpret_cast<const float4*>(
        Q + ((size_t)b * NPTS + q0) * 3);
    const float4 v0 = p4[0], v1 = p4[1], v2 = p4[2];
    const float4 v3 = p4[3], v4 = p4[4], v5 = p4[5];

    const float qx0 = v0.x, qy0 = v0.y, qz0 = v0.z;
    const float qx1 = v0.w, qy1 = v1.x, qz1 = v1.y;
    const float qx2 = v1.z, qy2 = v1.w, qz2 = v2.x;
    const float qx3 = v2.y, qy3 = v2.z, qz3 = v2.w;
    const float qx4 = v3.x, qy4 = v3.y, qz4 = v3.z;
    const float qx5 = v3.w, qy5 = v4.x, qz5 = v4.y;
    const float qx6 = v4.z, qy6 = v4.w, qz6 = v5.x;
    const float qx7 = v5.y, qy7 = v5.z, qz7 = v5.w;

    __syncthreads();

    float m0 = 3.4e38f, m1 = 3.4e38f, m2 = 3.4e38f, m3 = 3.4e38f;
    float m4 = 3.4e38f, m5 = 3.4e38f, m6 = 3.4e38f, m7 = 3.4e38f;

    // e = ||q-y||^2 - ||q||^2 = ||y||^2 - 2*dot(q,y)  (rx added in stage 2)
    #define DO_Q(k) \
        m##k = fminf(m##k, fmaf(qx##k, y.x, fmaf(qy##k, y.y, \
                                 fmaf(qz##k, y.z, y.w))));

    #pragma unroll 4
    for (int j = 0; j < SLICE; ++j) {
        const float4 y = sT[j];
        DO_Q(0) DO_Q(1) DO_Q(2) DO_Q(3)
        DO_Q(4) DO_Q(5) DO_Q(6) DO_Q(7)
    }
    #undef DO_Q

    // Combine partial mins across the 32 slices via uint atomicMin
    // (e + BIAS > 0, so the float bit pattern is uint-order-preserving).
    unsigned int* base = umin + (size_t)db * NPTS + q0;
    atomicMin(&base[0], __float_as_uint(m0 + BIAS));
    atomicMin(&base[1], __float_as_uint(m1 + BIAS));
    atomicMin(&base[2], __float_as_uint(m2 + BIAS));
    atomicMin(&base[3], __float_as_uint(m3 + BIAS));
    atomicMin(&base[4], __float_as_uint(m4 + BIAS));
    atomicMin(&base[5], __float_as_uint(m5 + BIAS));
    atomicMin(&base[6], __float_as_uint(m6 + BIAS));
    atomicMin(&base[7], __float_as_uint(m7 + BIAS));
}

// Stage 2: one thread per query; unbias, add rx, block-reduce, atomicAdd.
#define TPB2 256
__global__ __launch_bounds__(TPB2) void chamfer_stage2(
    const float* __restrict__ preds,
    const float* __restrict__ gts,
    const unsigned int* __restrict__ umin,
    float* __restrict__ out)
{
    const int g   = blockIdx.x * TPB2 + threadIdx.x;   // [0, 2*8*4096)
    const int db  = g >> 12;
    const int dir = db >> 3;
    const float* Q = dir ? gts : preds;
    const int bq  = ((db & 7) << 12) | (g & (NPTS - 1));

    const float x0 = Q[bq * 3 + 0];
    const float x1 = Q[bq * 3 + 1];
    const float x2 = Q[bq * 3 + 2];
    const float rx = x0 * x0 + x1 * x1 + x2 * x2;

    float s = (__uint_as_float(umin[g]) - BIAS) + rx;

    #pragma unroll
    for (int off = 32; off > 0; off >>= 1)
        s += __shfl_down(s, off, 64);

    __shared__ float red[TPB2 / 64];
    const int lane = threadIdx.x & 63;
    const int wid  = threadIdx.x >> 6;
    if (lane == 0) red[wid] = s;
    __syncthreads();
    if (threadIdx.x == 0) {
        float t = 0.0f;
        #pragma unroll
        for (int w = 0; w < TPB2 / 64; ++w) t += red[w];
        atomicAdd(out, t);
    }
}

extern "C" void kernel_launch(void* const* d_in, const int* in_sizes, int n_in,
                              void* d_out, int out_size, void* d_ws, size_t ws_size,
                              hipStream_t stream) {
    const float* preds = (const float*)d_in[0];
    const float* gts   = (const float*)d_in[1];
    float* out = (float*)d_out;
    unsigned int* umin = (unsigned int*)d_ws;   // 2*8*4096 uints = 256 KiB

    const size_t umin_bytes = (size_t)2 * BATCH * NPTS * sizeof(unsigned int);
    hipMemsetAsync(umin, 0xFF, umin_bytes, stream);   // uint max sentinel
    hipMemsetAsync(out, 0, sizeof(float), stream);

    chamfer_stage1<<<dim3(2 * BATCH * NSLICE), TPB1, 0, stream>>>(preds, gts, umin);
    chamfer_stage2<<<dim3(2 * BATCH * NPTS / TPB2), TPB2, 0, stream>>>(preds, gts, umin, out);
}

// Round 5
// 36.204 us; speedup vs baseline: 2.3607x; 2.3607x over previous
//
#include <hip/hip_runtime.h>

#define BATCH  8
#define NPTS   4096
#define NSLICE 16                 // target-set split per (dir,b)
#define SLICE  (NPTS / NSLICE)    // 256 targets per block
#define TPB1   512                // 8 waves/block, 1 block/CU
#define QPT    8                  // queries per thread (4096 / 512)

// Stage 1: grid = 2 dirs x 8 batches x 16 target-slices = 256 blocks.
// Each thread owns 8 queries in registers; block stages its 256-target
// slice in LDS packed as (-2y0,-2y1,-2y2,||y||^2). Partial per-query mins
// are written with PLAIN COALESCED STORES (32 B/thread) — the previous
// atomicMin design generated 64 MB of memory-side RMW traffic (device-scope
// atomics bypass the XCD-private L2) and was the entire bottleneck.
__global__ __launch_bounds__(TPB1, 2) void chamfer_stage1(
    const float* __restrict__ preds,
    const float* __restrict__ gts,
    float* __restrict__ part)     // [16 db][NSLICE][NPTS]
{
    const int blk   = blockIdx.x;
    const int slice = blk % NSLICE;
    const int db    = blk / NSLICE;    // dir*8 + b
    const int dir   = db >> 3;
    const int b     = db & 7;

    const float* Q = dir ? gts   : preds;   // query set
    const float* T = dir ? preds : gts;     // target set

    __shared__ float4 sT[SLICE];            // 4 KiB

    const float* Tb = T + ((size_t)b * NPTS + slice * SLICE) * 3;
    if (threadIdx.x < SLICE) {
        const int j = threadIdx.x;
        const float y0 = Tb[j * 3 + 0];
        const float y1 = Tb[j * 3 + 1];
        const float y2 = Tb[j * 3 + 2];
        sT[j] = make_float4(-2.0f * y0, -2.0f * y1, -2.0f * y2,
                            y0 * y0 + y1 * y1 + y2 * y2);
    }

    // This thread's 8 consecutive queries (24 floats = 6 float4).
    const int q0 = threadIdx.x * QPT;
    const float4* p4 = reinterpret_cast<const float4*>(
        Q + ((size_t)b * NPTS + q0) * 3);
    const float4 v0 = p4[0], v1 = p4[1], v2 = p4[2];
    const float4 v3 = p4[3], v4 = p4[4], v5 = p4[5];

    const float qx0 = v0.x, qy0 = v0.y, qz0 = v0.z;
    const float qx1 = v0.w, qy1 = v1.x, qz1 = v1.y;
    const float qx2 = v1.z, qy2 = v1.w, qz2 = v2.x;
    const float qx3 = v2.y, qy3 = v2.z, qz3 = v2.w;
    const float qx4 = v3.x, qy4 = v3.y, qz4 = v3.z;
    const float qx5 = v3.w, qy5 = v4.x, qz5 = v4.y;
    const float qx6 = v4.z, qy6 = v4.w, qz6 = v5.x;
    const float qx7 = v5.y, qy7 = v5.z, qz7 = v5.w;

    __syncthreads();

    float m0 = 3.4e38f, m1 = 3.4e38f, m2 = 3.4e38f, m3 = 3.4e38f;
    float m4 = 3.4e38f, m5 = 3.4e38f, m6 = 3.4e38f, m7 = 3.4e38f;

    // e = ||q-y||^2 - ||q||^2 = ||y||^2 - 2*dot(q,y)  (rx added in stage 2)
    #define DO_Q(k) \
        m##k = fminf(m##k, fmaf(qx##k, y.x, fmaf(qy##k, y.y, \
                                 fmaf(qz##k, y.z, y.w))));

    #pragma unroll 8
    for (int j = 0; j < SLICE; ++j) {
        const float4 y = sT[j];
        DO_Q(0) DO_Q(1) DO_Q(2) DO_Q(3)
        DO_Q(4) DO_Q(5) DO_Q(6) DO_Q(7)
    }
    #undef DO_Q

    // Coalesced 32 B/thread store of partial mins: part[db][slice][q0..q0+7]
    float* base = part + ((size_t)db * NSLICE + slice) * NPTS + q0;
    float4* b4 = reinterpret_cast<float4*>(base);
    b4[0] = make_float4(m0, m1, m2, m3);
    b4[1] = make_float4(m4, m5, m6, m7);
}

// Stage 2: one thread per query; min over the 16 slice-partials
// (lane-coalesced strided loads), add rx, block-reduce, one atomicAdd.
#define TPB2 256
__global__ __launch_bounds__(TPB2) void chamfer_stage2(
    const float* __restrict__ preds,
    const float* __restrict__ gts,
    const float* __restrict__ part,
    float* __restrict__ out)
{
    const int g   = blockIdx.x * TPB2 + threadIdx.x;   // [0, 2*8*4096)
    const int db  = g >> 12;
    const int q   = g & (NPTS - 1);
    const int dir = db >> 3;
    const int b   = db & 7;

    const float* pp = part + (size_t)db * NSLICE * NPTS + q;
    float m = 3.4e38f;
    #pragma unroll
    for (int s = 0; s < NSLICE; ++s)
        m = fminf(m, pp[(size_t)s * NPTS]);

    const float* Q = dir ? gts : preds;
    const size_t qi = ((size_t)b * NPTS + q) * 3;
    const float x0 = Q[qi + 0];
    const float x1 = Q[qi + 1];
    const float x2 = Q[qi + 2];
    float s = m + (x0 * x0 + x1 * x1 + x2 * x2);

    #pragma unroll
    for (int off = 32; off > 0; off >>= 1)
        s += __shfl_down(s, off, 64);

    __shared__ float red[TPB2 / 64];
    const int lane = threadIdx.x & 63;
    const int wid  = threadIdx.x >> 6;
    if (lane == 0) red[wid] = s;
    __syncthreads();
    if (threadIdx.x == 0) {
        float t = 0.0f;
        #pragma unroll
        for (int w = 0; w < TPB2 / 64; ++w) t += red[w];
        atomicAdd(out, t);
    }
}

extern "C" void kernel_launch(void* const* d_in, const int* in_sizes, int n_in,
                              void* d_out, int out_size, void* d_ws, size_t ws_size,
                              hipStream_t stream) {
    const float* preds = (const float*)d_in[0];
    const float* gts   = (const float*)d_in[1];
    float* out  = (float*)d_out;
    float* part = (float*)d_ws;   // 16 db x 16 slices x 4096 floats = 4 MiB

    // part is fully written by stage 1 before stage 2 reads it — no init.
    hipMemsetAsync(out, 0, sizeof(float), stream);

    chamfer_stage1<<<dim3(2 * BATCH * NSLICE), TPB1, 0, stream>>>(preds, gts, part);
    chamfer_stage2<<<dim3(2 * BATCH * NPTS / TPB2), TPB2, 0, stream>>>(preds, gts, part, out);
}